// Round 9
// baseline (2074.246 us; speedup 1.0000x reference)
//
#include <hip/hip_runtime.h>
#include <hip/hip_bf16.h>

// SerriformNet: B=2,S=1024,D=512,DM=128,E=2,DH=128,K=5,V=50257,L=4
#define Bsz 2
#define Ssz 1024
#define Dsz 512
#define DMs 128
#define Vsz 50257
#define ROWS (Bsz*Ssz)   // 2048

typedef __attribute__((ext_vector_type(8))) short short8;
typedef __attribute__((ext_vector_type(4))) float f32x4;
typedef __attribute__((ext_vector_type(8))) int int8v;
typedef __attribute__((ext_vector_type(4))) int int4v;

#define DEV static __device__ __forceinline__

DEV unsigned short f2bf(float f){
  unsigned int u = __float_as_uint(f);
  unsigned int r = ((u >> 16) & 1u) + 0x7fffu;
  return (unsigned short)((u + r) >> 16);
}

// async global->LDS, 16B per lane. LDS dest = wave-uniform base + lane*16.
DEV void gll16(const unsigned short* g, unsigned short* l) {
  __builtin_amdgcn_global_load_lds(
      (const __attribute__((address_space(1))) unsigned int*)(g),
      (__attribute__((address_space(3))) unsigned int*)(l), 16, 0, 0);
}

// ---------------- embed + rope ----------------
__global__ __launch_bounds__(256) void k_embed_rope(
    const int* __restrict__ tokens, const float* __restrict__ embed, float* __restrict__ x)
{
  int row = blockIdx.x;
  int s = row & (Ssz-1);
  int t = threadIdx.x;
  int tok = tokens[row];
  const float* e = embed + (size_t)tok * Dsz;
  float e1 = e[t], e2 = e[t + 256];
  float inv = powf(10000.f, -(float)t * (1.f/256.f));
  float fr = (float)s * inv;
  float sn, cs;
  sincosf(fr, &sn, &cs);
  float* o = x + (size_t)row * Dsz;
  o[t]       = e1 * cs - e2 * sn;
  o[t + 256] = e2 * cs + e1 * sn;
}

// ---------------- rmsnorm ----------------
__global__ __launch_bounds__(256) void k_rmsnorm(
    const float* __restrict__ a, const float* __restrict__ w, float* __restrict__ out)
{
  int row = blockIdx.x; int t = threadIdx.x;
  size_t base = (size_t)row * Dsz;
  float v0 = a[base + t];
  float v1 = a[base + t + 256];
  float ss = v0*v0 + v1*v1;
  #pragma unroll
  for (int off = 32; off > 0; off >>= 1) ss += __shfl_down(ss, off);
  __shared__ float sred[4];
  __shared__ float sscale;
  int wid = t >> 6, lane = t & 63;
  if (lane == 0) sred[wid] = ss;
  __syncthreads();
  if (t == 0) {
    float tot = sred[0] + sred[1] + sred[2] + sred[3];
    sscale = rsqrtf(tot * (1.f/Dsz) + 1e-6f);
  }
  __syncthreads();
  float sc = sscale;
  out[base + t]       = w[t]       * v0 * sc;
  out[base + t + 256] = w[t + 256] * v1 * sc;
}

// ---------------- rmsnorm -> bf16 (for logits A) ----------------
__global__ __launch_bounds__(256) void k_rmsnorm_b16(
    const float* __restrict__ a, const float* __restrict__ w, unsigned short* __restrict__ out)
{
  int row = blockIdx.x; int t = threadIdx.x;
  size_t base = (size_t)row * Dsz;
  float v0 = a[base + t];
  float v1 = a[base + t + 256];
  float ss = v0*v0 + v1*v1;
  #pragma unroll
  for (int off = 32; off > 0; off >>= 1) ss += __shfl_down(ss, off);
  __shared__ float sred[4];
  __shared__ float sscale;
  int wid = t >> 6, lane = t & 63;
  if (lane == 0) sred[wid] = ss;
  __syncthreads();
  if (t == 0) {
    float tot = sred[0] + sred[1] + sred[2] + sred[3];
    sscale = rsqrtf(tot * (1.f/Dsz) + 1e-6f);
  }
  __syncthreads();
  float sc = sscale;
  out[base + t]       = f2bf(w[t]       * v0 * sc);
  out[base + t + 256] = f2bf(w[t + 256] * v1 * sc);
}

// ---------------- combine experts + rmsnorm (fused) ----------------
__global__ __launch_bounds__(256) void k_combine_norm(
    const float* __restrict__ h, const float* __restrict__ e0,
    const float* __restrict__ e1, const float* __restrict__ rg,
    const float* __restrict__ w, float* __restrict__ out)
{
  int row = blockIdx.x; int t = threadIdx.x;
  size_t base = (size_t)row * Dsz;
  float r0 = rg[row*2], r1 = rg[row*2+1];
  float v0 = h[base + t]       + r0*e0[base + t]       + r1*e1[base + t];
  float v1 = h[base + t + 256] + r0*e0[base + t + 256] + r1*e1[base + t + 256];
  float ss = v0*v0 + v1*v1;
  #pragma unroll
  for (int off = 32; off > 0; off >>= 1) ss += __shfl_down(ss, off);
  __shared__ float sred[4];
  __shared__ float sscale;
  int wid = t >> 6, lane = t & 63;
  if (lane == 0) sred[wid] = ss;
  __syncthreads();
  if (t == 0) {
    float tot = sred[0] + sred[1] + sred[2] + sred[3];
    sscale = rsqrtf(tot * (1.f/Dsz) + 1e-6f);
  }
  __syncthreads();
  float sc = sscale;
  out[base + t]       = w[t]       * v0 * sc;
  out[base + t + 256] = w[t + 256] * v1 * sc;
}

// ---------------- fp32-in bf16 MFMA GEMM (128x128) — fallback logits ----------------
__global__ __launch_bounds__(256) void k_gemm128(
    const float* __restrict__ A, int lda,
    const float* __restrict__ B, int ldb,
    const float* __restrict__ bias,
    float* __restrict__ C, int ldc,
    int M, int N, int K)
{
  __shared__ __align__(16) unsigned short As[128][40];
  __shared__ __align__(16) unsigned short Bs[128][40];
  int t = threadIdx.x;
  int m0 = blockIdx.y * 128;
  int n0 = blockIdx.x * 128;
  int wid = t >> 6, lane = t & 63;
  int wr = wid >> 1, wc = wid & 1;
  f32x4 acc[4][4] = {};
  int tr = t >> 3;
  int tc = (t & 7) * 4;

  for (int k0 = 0; k0 < K; k0 += 32) {
    #pragma unroll
    for (int rr = 0; rr < 128; rr += 32) {
      int row = rr + tr;
      float4 av = *reinterpret_cast<const float4*>(A + (size_t)(m0 + row)*lda + k0 + tc);
      ushort4 ap; ap.x = f2bf(av.x); ap.y = f2bf(av.y); ap.z = f2bf(av.z); ap.w = f2bf(av.w);
      *reinterpret_cast<ushort4*>(&As[row][tc]) = ap;
      int bn = n0 + row;
      float4 bv = make_float4(0.f, 0.f, 0.f, 0.f);
      if (bn < N) bv = *reinterpret_cast<const float4*>(B + (size_t)bn*ldb + k0 + tc);
      ushort4 bp; bp.x = f2bf(bv.x); bp.y = f2bf(bv.y); bp.z = f2bf(bv.z); bp.w = f2bf(bv.w);
      *reinterpret_cast<ushort4*>(&Bs[row][tc]) = bp;
    }
    __syncthreads();
    int kc = (lane >> 4) * 8;
    int ra = lane & 15;
    short8 af[4], bf_[4];
    #pragma unroll
    for (int mt = 0; mt < 4; ++mt)
      af[mt] = *reinterpret_cast<const short8*>(&As[wr*64 + mt*16 + ra][kc]);
    #pragma unroll
    for (int nt = 0; nt < 4; ++nt)
      bf_[nt] = *reinterpret_cast<const short8*>(&Bs[wc*64 + nt*16 + ra][kc]);
    #pragma unroll
    for (int mt = 0; mt < 4; ++mt)
      #pragma unroll
      for (int nt = 0; nt < 4; ++nt)
        acc[mt][nt] = __builtin_amdgcn_mfma_f32_16x16x32_bf16(af[mt], bf_[nt], acc[mt][nt], 0, 0, 0);
    __syncthreads();
  }

  #pragma unroll
  for (int mt = 0; mt < 4; ++mt) {
    #pragma unroll
    for (int nt = 0; nt < 4; ++nt) {
      int n = n0 + wc*64 + nt*16 + (lane & 15);
      if (n >= N) continue;
      float bv = bias ? bias[n] : 0.f;
      #pragma unroll
      for (int j = 0; j < 4; ++j) {
        int m = m0 + wr*64 + mt*16 + (lane >> 4)*4 + j;
        C[(size_t)m*ldc + n] = acc[mt][nt][j] + bv;
      }
    }
  }
}

// ---------------- 64x64-tile GEMM body ----------------
template<int OP, int NADD>
DEV void gemm64_body(unsigned short (*As)[40], unsigned short (*Bs)[40],
                     const float* __restrict__ A, int lda,
                     const float* __restrict__ B, int ldb,
                     const float* __restrict__ bias,
                     float* __restrict__ C, int ldc,
                     int K, int m0, int n0, int t,
                     const float* __restrict__ add1,
                     const float* __restrict__ add2,
                     const float* __restrict__ add3)
{
  int lane = t & 63;
  int wid = t >> 6;
  int wr = wid >> 1, wc = wid & 1;
  f32x4 acc[2][2] = {};
  int srow = t >> 2;
  int scb  = (t & 3) * 8;

  const float* apg = A + (size_t)(m0 + srow)*lda + scb;
  const float* bpg = B + (size_t)(n0 + srow)*ldb + scb;

  for (int k0 = 0; k0 < K; k0 += 32) {
    float4 a0 = *reinterpret_cast<const float4*>(apg + k0);
    float4 a1 = *reinterpret_cast<const float4*>(apg + k0 + 4);
    float4 b0 = *reinterpret_cast<const float4*>(bpg + k0);
    float4 b1 = *reinterpret_cast<const float4*>(bpg + k0 + 4);
    short8 av, bv;
    av[0]=f2bf(a0.x); av[1]=f2bf(a0.y); av[2]=f2bf(a0.z); av[3]=f2bf(a0.w);
    av[4]=f2bf(a1.x); av[5]=f2bf(a1.y); av[6]=f2bf(a1.z); av[7]=f2bf(a1.w);
    bv[0]=f2bf(b0.x); bv[1]=f2bf(b0.y); bv[2]=f2bf(b0.z); bv[3]=f2bf(b0.w);
    bv[4]=f2bf(b1.x); bv[5]=f2bf(b1.y); bv[6]=f2bf(b1.z); bv[7]=f2bf(b1.w);
    *reinterpret_cast<short8*>(&As[srow][scb]) = av;
    *reinterpret_cast<short8*>(&Bs[srow][scb]) = bv;
    __syncthreads();
    int kc = (lane >> 4) * 8;
    int ra = lane & 15;
    short8 af[2], bf_[2];
    #pragma unroll
    for (int mt = 0; mt < 2; ++mt)
      af[mt] = *reinterpret_cast<const short8*>(&As[wr*32 + mt*16 + ra][kc]);
    #pragma unroll
    for (int nt = 0; nt < 2; ++nt)
      bf_[nt] = *reinterpret_cast<const short8*>(&Bs[wc*32 + nt*16 + ra][kc]);
    #pragma unroll
    for (int mt = 0; mt < 2; ++mt)
      #pragma unroll
      for (int nt = 0; nt < 2; ++nt)
        acc[mt][nt] = __builtin_amdgcn_mfma_f32_16x16x32_bf16(af[mt], bf_[nt], acc[mt][nt], 0, 0, 0);
    __syncthreads();
  }

  #pragma unroll
  for (int mt = 0; mt < 2; ++mt) {
    #pragma unroll
    for (int nt = 0; nt < 2; ++nt) {
      int n = n0 + wc*32 + nt*16 + (lane & 15);
      float bv = bias ? bias[n] : 0.f;
      #pragma unroll
      for (int j = 0; j < 4; ++j) {
        int m = m0 + wr*32 + mt*16 + (lane >> 4)*4 + j;
        float v = acc[mt][nt][j] + bv;
        if (OP == 1) v = v / (1.f + expf(-v));
        else if (OP == 2) v = 0.5f * v * (1.f + erff(v * 0.70710678118f));
        size_t idx = (size_t)m*ldc + n;
        if (NADD >= 1) v += add1[idx];
        if (NADD >= 2) v += add2[idx];
        if (NADD >= 3) v += add3[idx];
        C[idx] = v;
      }
    }
  }
}

// ---------------- standalone 64x64 GEMM ----------------
template<int OP, int NADD>
__global__ __launch_bounds__(256) void k_gemm64(
    const float* __restrict__ A, int lda,
    const float* __restrict__ B, int ldb,
    const float* __restrict__ bias,
    float* __restrict__ C, int ldc, int K,
    const float* add1, const float* add2, const float* add3)
{
  __shared__ __align__(16) unsigned short As[64][40];
  __shared__ __align__(16) unsigned short Bs[64][40];
  gemm64_body<OP,NADD>(As, Bs, A, lda, B, ldb, bias, C, ldc, K,
                       blockIdx.y*64, blockIdx.x*64, threadIdx.x, add1, add2, add3);
}

// ---------------- fused: dwconv (blocks x>=6) + 3 recurrence projections ----------------
__global__ __launch_bounds__(256) void k_dwproj3(
    const float* __restrict__ xn,
    const float* __restrict__ rin_w, const float* __restrict__ rin_b,
    const float* __restrict__ rf_w,  const float* __restrict__ rf_b,
    const float* __restrict__ ru_w,  const float* __restrict__ ru_b,
    float* __restrict__ mu, float* __restrict__ fx, float* __restrict__ ux,
    const float* __restrict__ dw_w, const float* __restrict__ dw_b,
    float* __restrict__ dout, int dil)
{
  __shared__ __align__(16) unsigned short As[64][40];
  __shared__ __align__(16) unsigned short Bs[64][40];
  if (blockIdx.x >= 6) {
    int row = (blockIdx.x - 6)*32 + blockIdx.y;
    int b = row >> 10, s = row & (Ssz-1);
    int t = threadIdx.x;
    #pragma unroll
    for (int dd = 0; dd < 2; ++dd) {
      int d = t + dd*256;
      float acc = dw_b[d];
      #pragma unroll
      for (int j = 0; j < 5; ++j) {
        int sp = s - (4 - j) * dil;
        if (sp >= 0) acc += dw_w[d*5 + j] * xn[((size_t)(b*Ssz + sp))*Dsz + d];
      }
      dout[(size_t)row*Dsz + d] = acc;
    }
    return;
  }
  int which = blockIdx.x >> 1;          // 0:mu 1:fx 2:ux
  int n0 = (blockIdx.x & 1) * 64;
  int m0 = blockIdx.y * 64;
  if (which == 0)
    gemm64_body<1,0>(As, Bs, xn, Dsz, rin_w, Dsz, rin_b, mu, DMs, Dsz, m0, n0, threadIdx.x, nullptr, nullptr, nullptr);
  else if (which == 1)
    gemm64_body<0,0>(As, Bs, xn, Dsz, rf_w, 640, rf_b, fx, DMs, Dsz, m0, n0, threadIdx.x, nullptr, nullptr, nullptr);
  else
    gemm64_body<0,0>(As, Bs, xn, Dsz, ru_w, 640, ru_b, ux, DMs, Dsz, m0, n0, threadIdx.x, nullptr, nullptr, nullptr);
}

// ---------------- batched expert pair (+ optional folded router softmax) ----------------
template<int OP, int RT>
__global__ __launch_bounds__(256) void k_expair(
    const float* __restrict__ A0, const float* __restrict__ A1, int lda,
    const float* __restrict__ B0, const float* __restrict__ B1, int ldb,
    const float* __restrict__ bias0, const float* __restrict__ bias1,
    float* __restrict__ C0, float* __restrict__ C1, int ldc, int K,
    const float* __restrict__ rtw, const float* __restrict__ rtb,
    float* __restrict__ rg)
{
  __shared__ __align__(16) unsigned short As[64][40];
  __shared__ __align__(16) unsigned short Bs[64][40];
  if (RT && blockIdx.x >= 16) {
    int lane = threadIdx.x & 63, wid = threadIdx.x >> 6;
    #pragma unroll 1
    for (int it = 0; it < 16; ++it) {
      int row = blockIdx.y*64 + it*4 + wid;
      const float* hp = A0 + (size_t)row*Dsz;
      float a0 = 0.f, a1 = 0.f;
      #pragma unroll
      for (int k = lane; k < Dsz; k += 64) {
        float hv = hp[k];
        a0 += hv * rtw[k];
        a1 += hv * rtw[Dsz + k];
      }
      #pragma unroll
      for (int off = 32; off > 0; off >>= 1) {
        a0 += __shfl_down(a0, off);
        a1 += __shfl_down(a1, off);
      }
      if (lane == 0) {
        a0 += rtb[0]; a1 += rtb[1];
        float mx = fmaxf(a0, a1);
        float e0 = expf(a0 - mx), e1 = expf(a1 - mx);
        float s = e0 + e1;
        rg[row*2]     = e0 / s;
        rg[row*2 + 1] = e1 / s;
      }
    }
    return;
  }
  int e = blockIdx.x >> 3;
  int n0 = (blockIdx.x & 7) * 64;
  gemm64_body<OP,0>(As, Bs, e ? A1 : A0, lda, e ? B1 : B0, ldb,
                    e ? bias1 : bias0, e ? C1 : C0, ldc, K,
                    blockIdx.y*64, n0, threadIdx.x, nullptr, nullptr, nullptr);
}

// ---------------- fp32 -> bf16 convert ----------------
__global__ __launch_bounds__(256) void k_f2b(
    const float* __restrict__ in, unsigned short* __restrict__ o, int n8)
{
  int stride = gridDim.x * 256;
  for (int i = blockIdx.x*256 + threadIdx.x; i < n8; i += stride) {
    float4 a = reinterpret_cast<const float4*>(in)[i*2];
    float4 b = reinterpret_cast<const float4*>(in)[i*2+1];
    short8 v;
    v[0]=f2bf(a.x); v[1]=f2bf(a.y); v[2]=f2bf(a.z); v[3]=f2bf(a.w);
    v[4]=f2bf(b.x); v[5]=f2bf(b.y); v[6]=f2bf(b.z); v[7]=f2bf(b.w);
    *reinterpret_cast<short8*>(o + (size_t)i*8) = v;
  }
}

// ---------------- bf16-in GEMM for logits: m97-style global_load_lds staging ----------------
// A/B retry of the round-7 kernel WITHOUT the confounding f2b fold (r7 = both,
// r8 = neither, r9 = this only). m97 hit 874 TF refcheck'd with exactly this
// structure (linear LDS, width-16 gload_lds, 2 barriers, 128x32 tile).
__global__ __launch_bounds__(256) void k_gemm_logits(
    const unsigned short* __restrict__ A, const unsigned short* __restrict__ B,
    float* __restrict__ C, int M, int N, int K)
{
  __shared__ __align__(16) unsigned short As[4096];   // 128 x 32 shorts, linear
  __shared__ __align__(16) unsigned short Bs[4096];
  int t = threadIdx.x;
  // XCD-aware swizzle: grid fixed 16 x 393 = 6288 blocks, 6288 % 8 == 0 -> bijective.
  int lin = blockIdx.x + blockIdx.y * 16;
  int swz = (lin & 7) * 786 + (lin >> 3);
  int m0 = (swz & 15) * 128;
  int n0 = (swz >> 4) * 128;
  int wid = t >> 6, lane = t & 63;
  int wr = wid >> 1, wc = wid & 1;
  f32x4 acc[4][4] = {};

  // staging chunk geometry: chunk c -> row c>>2, k-byte (c&3)*16
  int row0 = t >> 2;
  int kcb  = (t & 3) * 8;        // shorts
  int row1 = row0 + 64;          // chunk t+256
  const unsigned short* a0p = A + (size_t)(m0 + row0)*K + kcb;
  const unsigned short* a1p = A + (size_t)(m0 + row1)*K + kcb;
  int bn0 = n0 + row0; if (bn0 >= N) bn0 = N - 1;
  int bn1 = n0 + row1; if (bn1 >= N) bn1 = N - 1;
  const unsigned short* b0p = B + (size_t)bn0*K + kcb;
  const unsigned short* b1p = B + (size_t)bn1*K + kcb;

  unsigned short* lA0 = As + wid*512;          // bytes: wid*1024
  unsigned short* lA1 = As + 2048 + wid*512;   // bytes: 4096 + wid*1024
  unsigned short* lB0 = Bs + wid*512;
  unsigned short* lB1 = Bs + 2048 + wid*512;

  int kc = (lane >> 4) * 8;
  int ra = lane & 15;

  for (int k0 = 0; k0 < K; k0 += 32) {
    gll16(a0p + k0, lA0);
    gll16(a1p + k0, lA1);
    gll16(b0p + k0, lB0);
    gll16(b1p + k0, lB1);
    __syncthreads();               // compiler drains vmcnt before s_barrier
    short8 af[4], bf_[4];
    #pragma unroll
    for (int mt = 0; mt < 4; ++mt)
      af[mt] = *reinterpret_cast<const short8*>(As + (wr*64 + mt*16 + ra)*32 + kc);
    #pragma unroll
    for (int nt = 0; nt < 4; ++nt)
      bf_[nt] = *reinterpret_cast<const short8*>(Bs + (wc*64 + nt*16 + ra)*32 + kc);
    #pragma unroll
    for (int mt = 0; mt < 4; ++mt)
      #pragma unroll
      for (int nt = 0; nt < 4; ++nt)
        acc[mt][nt] = __builtin_amdgcn_mfma_f32_16x16x32_bf16(af[mt], bf_[nt], acc[mt][nt], 0, 0, 0);
    __syncthreads();
  }

  #pragma unroll
  for (int mt = 0; mt < 4; ++mt) {
    #pragma unroll
    for (int nt = 0; nt < 4; ++nt) {
      int n = n0 + wc*64 + nt*16 + (lane & 15);
      if (n >= N) continue;
      #pragma unroll
      for (int j = 0; j < 4; ++j) {
        int m = m0 + wr*64 + mt*16 + (lane >> 4)*4 + j;
        C[(size_t)m*N + n] = acc[mt][nt][j];
      }
    }
  }
}

// ---------------- fused: MFMA scan v10 (blocks 0,1) + two 64² GEMMs ----------------
// Scan loop FROZEN (round-8 verbatim): serial latency chain ~790cyc/step;
// sched_barrier/unroll/dtype/fold probes all failed to cut it.
__global__ __launch_bounds__(256, 2) void k_scan_fused(
    const float* __restrict__ rf_w, const float* __restrict__ ru_w,
    const float* __restrict__ fx, const float* __restrict__ ux,
    const float* __restrict__ mu, float* __restrict__ Mout,
    const float* __restrict__ g1A, const float* __restrict__ g1B, int g1ldb,
    const float* __restrict__ g1bias, float* __restrict__ g1C,
    const float* __restrict__ g2A, const float* __restrict__ g2B, int g2ldb,
    const float* __restrict__ g2bias, float* __restrict__ g2C)
{
  __shared__ __align__(16) unsigned short As[64][40];
  __shared__ __align__(16) unsigned short Bs[64][40];
  __shared__ __align__(16) unsigned char mf8[2][DMs];

  if (blockIdx.x >= 2) {
    int bid = blockIdx.x - 2;
    int which = bid >> 8;
    int idx = bid & 255;
    int n0 = (idx & 7) * 64;
    int m0 = (idx >> 3) * 64;
    if (which == 0)
      gemm64_body<0,0>(As, Bs, g1A, Dsz, g1B, g1ldb, g1bias, g1C, Dsz, Dsz, m0, n0, threadIdx.x, nullptr, nullptr, nullptr);
    else
      gemm64_body<0,0>(As, Bs, g2A, Dsz, g2B, g2ldb, g2bias, g2C, Dsz, Dsz, m0, n0, threadIdx.x, nullptr, nullptr, nullptr);
    return;
  }

  // scan path: latency-critical; win pipe arbitration vs co-resident GEMM waves
  __builtin_amdgcn_s_setprio(1);

  int b = blockIdx.x;
  int t = threadIdx.x;
  int l = t & 63;
  int w = t >> 6;
  int g = l >> 4;
  int i16 = l & 15;

  // Weights in fp8 e4m3: lane l holds row (tile, i16), k = g*32 .. g*32+31 (32 bytes = 8 VGPRs).
  int8v w8[4];
  #pragma unroll
  for (int rt = 0; rt < 4; ++rt) {
    const float* src = (rt < 2 ? rf_w : ru_w) + (size_t)(w*32 + (rt&1)*16 + i16)*640 + 512 + g*32;
    int8v v;
    #pragma unroll
    for (int bq = 0; bq < 8; ++bq) {
      float4 f4 = *reinterpret_cast<const float4*>(src + bq*4);
      int rr = 0;
      rr = __builtin_amdgcn_cvt_pk_fp8_f32(f4.x, f4.y, rr, false);
      rr = __builtin_amdgcn_cvt_pk_fp8_f32(f4.z, f4.w, rr, true);
      v[bq] = rr;
    }
    w8[rt] = v;
  }

  if (t < DMs) mf8[0][t] = 0;   // fp8 0.0 == 0x00

  bool writer = (i16 & 4) == 0;
  int rho = ((i16 >> 3) << 4) + (g << 2) + (i16 & 3);
  int r = w*32 + rho;
  bool jb0 = (i16 & 1), jb1 = (i16 & 2), ab = (i16 & 8);

  const float* fxp = fx + (size_t)b*Ssz*DMs + r;
  const float* uxp = ux + (size_t)b*Ssz*DMs + r;
  const float* mup = mu + (size_t)b*Ssz*DMs + r;
  float* mo = Mout + (size_t)b*Ssz*DMs + r;
  float mreg = 0.f, fxv = 0.f, uxv = 0.f, muv = 0.f;
  __syncthreads();
  if (writer) { fxv = fxp[0]; uxv = uxp[0]; muv = mup[0]; }

  const int SC = 0x7F7F7F7F;    // E8M0 = 127 -> scale 1.0 in all 4 bytes
  int cur = 0;
  for (int step = 0; step < Ssz; ++step) {
    int4v blo = *reinterpret_cast<const int4v*>(&mf8[cur][g*32]);
    int4v bhi = *reinterpret_cast<const int4v*>(&mf8[cur][g*32 + 16]);
    int8v bm;
    bm[0]=blo[0]; bm[1]=blo[1]; bm[2]=blo[2]; bm[3]=blo[3];
    bm[4]=bhi[0]; bm[5]=bhi[1]; bm[6]=bhi[2]; bm[7]=bhi[3];

    f32x4 zero = {0.f, 0.f, 0.f, 0.f};
    f32x4 a0 = __builtin_amdgcn_mfma_scale_f32_16x16x128_f8f6f4(w8[0], bm, zero, 0, 0, 0, SC, 0, SC);
    f32x4 a1 = __builtin_amdgcn_mfma_scale_f32_16x16x128_f8f6f4(w8[1], bm, zero, 0, 0, 0, SC, 0, SC);
    f32x4 a2 = __builtin_amdgcn_mfma_scale_f32_16x16x128_f8f6f4(w8[2], bm, zero, 0, 0, 0, SC, 0, SC);
    f32x4 a3 = __builtin_amdgcn_mfma_scale_f32_16x16x128_f8f6f4(w8[3], bm, zero, 0, 0, 0, SC, 0, SC);

    float f01 = jb0 ? a0[1] : a0[0];
    float f23 = jb0 ? a0[3] : a0[2];
    float fa0 = jb1 ? f23 : f01;
    float f01b = jb0 ? a1[1] : a1[0];
    float f23b = jb0 ? a1[3] : a1[2];
    float fa1 = jb1 ? f23b : f01b;
    float zf = ab ? fa1 : fa0;
    float u01 = jb0 ? a2[1] : a2[0];
    float u23 = jb0 ? a2[3] : a2[2];
    float ua0 = jb1 ? u23 : u01;
    float u01b = jb0 ? a3[1] : a3[0];
    float u23b = jb0 ? a3[3] : a3[2];
    float ua1 = jb1 ? u23b : u01b;
    float zu = ab ? ua1 : ua0;

    if (writer) {
      float f = __builtin_amdgcn_rcpf(1.f + __expf(-(zf + fxv)));
      float u = __builtin_amdgcn_rcpf(1.f + __expf(-(zu + uxv)));
      float mnew = f*mreg + u*muv;
      mreg = mnew;
      int p8 = __builtin_amdgcn_cvt_pk_fp8_f32(mnew, mnew, 0, false);
      mf8[cur^1][r] = (unsigned char)(p8 & 0xff);
      mo[(size_t)step*DMs] = mnew;
      if (step < Ssz-1) {
        fxv = fxp[(size_t)(step+1)*DMs];
        uxv = uxp[(size_t)(step+1)*DMs];
        muv = mup[(size_t)(step+1)*DMs];
      }
    }
    asm volatile("s_waitcnt lgkmcnt(0)\n\ts_barrier" ::: "memory");
    cur ^= 1;
  }
}

// ---------------- host ----------------
extern "C" void kernel_launch(void* const* d_in, const int* in_sizes, int n_in,
                              void* d_out, int out_size, void* d_ws, size_t ws_size,
                              hipStream_t stream)
{
  const int*   tokens = (const int*)  d_in[0];
  const float* embed  = (const float*)d_in[1];
  const float* norm_w = (const float*)d_in[2];
  const float* dw_w   = (const float*)d_in[3];
  const float* dw_b   = (const float*)d_in[4];
  const float* pw_w   = (const float*)d_in[5];
  const float* pw_b   = (const float*)d_in[6];
  const float* rin_w  = (const float*)d_in[7];
  const float* rin_b  = (const float*)d_in[8];
  const float* rf_w   = (const float*)d_in[9];
  const float* rf_b   = (const float*)d_in[10];
  const float* ru_w   = (const float*)d_in[11];
  const float* ru_b   = (const float*)d_in[12];
  const float* ro_w   = (const float*)d_in[13];
  const float* ro_b   = (const float*)d_in[14];
  const float* rt_w   = (const float*)d_in[15];
  const float* rt_b   = (const float*)d_in[16];
  const float* e1_w   = (const float*)d_in[17];
  const float* e1_b   = (const float*)d_in[18];
  const float* e2_w   = (const float*)d_in[19];
  const float* e2_b   = (const float*)d_in[20];
  const float* fn_w   = (const float*)d_in[21];
  const float* fd_w   = (const float*)d_in[22];
  const float* fd_b   = (const float*)d_in[23];
  const float* fu_w   = (const float*)d_in[24];
  const float* fu_b   = (const float*)d_in[25];
  const float* fnorm  = (const float*)d_in[26];
  float* out = (float*)d_out;

  float* ws = (float*)d_ws;
  const size_t M1 = 1u << 20;
  float* x   = ws + 0*M1;
  float* xn  = ws + 1*M1;
  float* b2  = ws + 2*M1;
  float* b3  = ws + 3*M1;
  float* h   = ws + 4*M1;
  float* b5  = ws + 5*M1;
  float* b6  = ws + 6*M1;          // expert-1 e2 output (ROWS x Dsz = exactly M1 floats)
  float* mu  = ws + 7*M1;
  float* fx  = ws + 7*M1 + 262144;
  float* ux  = ws + 7*M1 + 2*262144;
  float* Mb  = ws + 7*M1 + 3*262144;
  float* g   = ws + 8*M1;          // ROWS x DMs only (262144 floats) — rg lives right after!
  float* rg  = ws + 8*M1 + 262144;
  const size_t EMB_ELEMS = (size_t)Vsz * Dsz;
  unsigned short* embb = (unsigned short*)(ws + 9*M1);
  bool big = ws_size >= (size_t)(9*M1*4) + EMB_ELEMS*2 + 1024;

  const int dils[4] = {1, 1, 2, 4};

  k_embed_rope<<<ROWS, 256, 0, stream>>>(tokens, embed, x);

  for (int i = 0; i < 4; ++i) {
    k_rmsnorm<<<ROWS,256,0,stream>>>(x, norm_w + i*Dsz, xn);
    // fused: dwconv (xn->b2) + recurrence projections mu/fx/ux, one dispatch
    {
      dim3 gr(70, 32);
      k_dwproj3<<<gr,256,0,stream>>>(xn,
          rin_w + (size_t)i*DMs*Dsz, rin_b + i*DMs,
          rf_w  + (size_t)i*DMs*640, rf_b  + i*DMs,
          ru_w  + (size_t)i*DMs*640, ru_b  + i*DMs,
          mu, fx, ux,
          dw_w + i*Dsz*5, dw_b + i*Dsz, b2, dils[i]);
    }
    // fused: scan (blocks 0,1) + pw GEMM (b2->b3) + ox GEMM (xn->b5)
    k_scan_fused<<<2 + 512, 256, 0, stream>>>(
        rf_w + (size_t)i*DMs*640, ru_w + (size_t)i*DMs*640, fx, ux, mu, Mb,
        b2, pw_w + (size_t)i*Dsz*Dsz, Dsz, pw_b + i*Dsz, b3,
        xn, ro_w + (size_t)i*Dsz*640, 640, ro_b + i*Dsz, b5);
    // wom projection, fused: h = gemm + xc + xn + ox
    {
      dim3 gr(Dsz/64, ROWS/64);
      k_gemm64<0,3><<<gr,256,0,stream>>>(Mb,DMs, ro_w + (size_t)i*Dsz*640 + 512,640, nullptr, h,Dsz, DMs, b3, xn, b5);
    }
    // experts pair-batched; router softmax folded into the e1 dispatch (blocks x==16)
    {
      dim3 ge1(17, ROWS/64), ge0(16, ROWS/64);
      k_expair<1,1><<<ge1,256,0,stream>>>(h, h, Dsz,
          e1_w + (size_t)(i*2+0)*Dsz*Dsz, e1_w + (size_t)(i*2+1)*Dsz*Dsz, Dsz,
          e1_b + (i*2+0)*Dsz, e1_b + (i*2+1)*Dsz,
          b2, b5, Dsz, Dsz,
          rt_w + i*2*Dsz, rt_b + i*2, rg);
      k_expair<0,0><<<ge0,256,0,stream>>>(b2, b5, Dsz,
          e2_w + (size_t)(i*2+0)*Dsz*Dsz, e2_w + (size_t)(i*2+1)*Dsz*Dsz, Dsz,
          e2_b + (i*2+0)*Dsz, e2_b + (i*2+1)*Dsz,
          b3, b6, Dsz, Dsz,
          nullptr, nullptr, nullptr);
    }
    // hn = rmsnorm(h + r0*e0 + r1*e1)
    k_combine_norm<<<ROWS,256,0,stream>>>(h, b3, b6, rg, fn_w + i*Dsz, xn);
    // FFN: g = gelu(...); x = x + xn + g@fu^T + fu_b
    {
      dim3 g1(DMs/64, ROWS/64), g2(Dsz/64, ROWS/64);
      k_gemm64<2,0><<<g1,256,0,stream>>>(xn,Dsz, fd_w + (size_t)i*DMs*Dsz,Dsz, fd_b + i*DMs, g,DMs, Dsz, nullptr,nullptr,nullptr);
      k_gemm64<0,2><<<g2,256,0,stream>>>(g,DMs, fu_w + (size_t)i*Dsz*DMs,DMs, fu_b + i*Dsz, x,Dsz, DMs, x, xn, nullptr);
    }
  }

  if (big) {
    unsigned short* xnb = (unsigned short*)b3;
    k_rmsnorm_b16<<<ROWS,256,0,stream>>>(x, fnorm, xnb);   // bf16 direct
    k_f2b<<<2048,256,0,stream>>>(embed, embb, (int)(EMB_ELEMS/8));
    dim3 grid(ROWS/128, (Vsz + 127)/128);
    k_gemm_logits<<<grid,256,0,stream>>>(xnb, embb, out, ROWS, Vsz, Dsz);
  } else {
    k_rmsnorm<<<ROWS,256,0,stream>>>(x, fnorm, xn);
    dim3 grid((Vsz + 127)/128, ROWS/128);
    k_gemm128<<<grid,256,0,stream>>>(xn,Dsz, embed,Dsz, nullptr, out,Vsz, ROWS,Vsz,Dsz);
  }
}

// Round 10
// 2058.130 us; speedup vs baseline: 1.0078x; 1.0078x over previous
//
#include <hip/hip_runtime.h>
#include <hip/hip_bf16.h>

// SerriformNet: B=2,S=1024,D=512,DM=128,E=2,DH=128,K=5,V=50257,L=4
#define Bsz 2
#define Ssz 1024
#define Dsz 512
#define DMs 128
#define Vsz 50257
#define ROWS (Bsz*Ssz)   // 2048

typedef __attribute__((ext_vector_type(8))) short short8;
typedef __attribute__((ext_vector_type(4))) float f32x4;
typedef __attribute__((ext_vector_type(8))) int int8v;
typedef __attribute__((ext_vector_type(4))) int int4v;

#define DEV static __device__ __forceinline__

DEV unsigned short f2bf(float f){
  unsigned int u = __float_as_uint(f);
  unsigned int r = ((u >> 16) & 1u) + 0x7fffu;
  return (unsigned short)((u + r) >> 16);
}

// ---------------- embed + rope ----------------
__global__ __launch_bounds__(256) void k_embed_rope(
    const int* __restrict__ tokens, const float* __restrict__ embed, float* __restrict__ x)
{
  int row = blockIdx.x;
  int s = row & (Ssz-1);
  int t = threadIdx.x;
  int tok = tokens[row];
  const float* e = embed + (size_t)tok * Dsz;
  float e1 = e[t], e2 = e[t + 256];
  float inv = powf(10000.f, -(float)t * (1.f/256.f));
  float fr = (float)s * inv;
  float sn, cs;
  sincosf(fr, &sn, &cs);
  float* o = x + (size_t)row * Dsz;
  o[t]       = e1 * cs - e2 * sn;
  o[t + 256] = e2 * cs + e1 * sn;
}

// ---------------- rmsnorm ----------------
__global__ __launch_bounds__(256) void k_rmsnorm(
    const float* __restrict__ a, const float* __restrict__ w, float* __restrict__ out)
{
  int row = blockIdx.x; int t = threadIdx.x;
  size_t base = (size_t)row * Dsz;
  float v0 = a[base + t];
  float v1 = a[base + t + 256];
  float ss = v0*v0 + v1*v1;
  #pragma unroll
  for (int off = 32; off > 0; off >>= 1) ss += __shfl_down(ss, off);
  __shared__ float sred[4];
  __shared__ float sscale;
  int wid = t >> 6, lane = t & 63;
  if (lane == 0) sred[wid] = ss;
  __syncthreads();
  if (t == 0) {
    float tot = sred[0] + sred[1] + sred[2] + sred[3];
    sscale = rsqrtf(tot * (1.f/Dsz) + 1e-6f);
  }
  __syncthreads();
  float sc = sscale;
  out[base + t]       = w[t]       * v0 * sc;
  out[base + t + 256] = w[t + 256] * v1 * sc;
}

// ---------------- final prep: rmsnorm->bf16 (blocks<ROWS) + embed f2b (rest) ----------------
// The only two mutually-independent dispatches left in the program; fused to save
// a launch gap and overlap two memory-bound passes.
__global__ __launch_bounds__(256) void k_final_prep(
    const float* __restrict__ a, const float* __restrict__ w, unsigned short* __restrict__ out,
    const float* __restrict__ esrc, unsigned short* __restrict__ edst, int n8)
{
  if (blockIdx.x >= ROWS) {
    int nb = gridDim.x - ROWS;
    int stride = nb * 256;
    for (int i = (blockIdx.x - ROWS)*256 + threadIdx.x; i < n8; i += stride) {
      float4 p = reinterpret_cast<const float4*>(esrc)[i*2];
      float4 q = reinterpret_cast<const float4*>(esrc)[i*2+1];
      short8 v;
      v[0]=f2bf(p.x); v[1]=f2bf(p.y); v[2]=f2bf(p.z); v[3]=f2bf(p.w);
      v[4]=f2bf(q.x); v[5]=f2bf(q.y); v[6]=f2bf(q.z); v[7]=f2bf(q.w);
      *reinterpret_cast<short8*>(edst + (size_t)i*8) = v;
    }
    return;
  }
  int row = blockIdx.x; int t = threadIdx.x;
  size_t base = (size_t)row * Dsz;
  float v0 = a[base + t];
  float v1 = a[base + t + 256];
  float ss = v0*v0 + v1*v1;
  #pragma unroll
  for (int off = 32; off > 0; off >>= 1) ss += __shfl_down(ss, off);
  __shared__ float sred[4];
  __shared__ float sscale;
  int wid = t >> 6, lane = t & 63;
  if (lane == 0) sred[wid] = ss;
  __syncthreads();
  if (t == 0) {
    float tot = sred[0] + sred[1] + sred[2] + sred[3];
    sscale = rsqrtf(tot * (1.f/Dsz) + 1e-6f);
  }
  __syncthreads();
  float sc = sscale;
  out[base + t]       = f2bf(w[t]       * v0 * sc);
  out[base + t + 256] = f2bf(w[t + 256] * v1 * sc);
}

// ---------------- combine experts + rmsnorm (fused) ----------------
__global__ __launch_bounds__(256) void k_combine_norm(
    const float* __restrict__ h, const float* __restrict__ e0,
    const float* __restrict__ e1, const float* __restrict__ rg,
    const float* __restrict__ w, float* __restrict__ out)
{
  int row = blockIdx.x; int t = threadIdx.x;
  size_t base = (size_t)row * Dsz;
  float r0 = rg[row*2], r1 = rg[row*2+1];
  float v0 = h[base + t]       + r0*e0[base + t]       + r1*e1[base + t];
  float v1 = h[base + t + 256] + r0*e0[base + t + 256] + r1*e1[base + t + 256];
  float ss = v0*v0 + v1*v1;
  #pragma unroll
  for (int off = 32; off > 0; off >>= 1) ss += __shfl_down(ss, off);
  __shared__ float sred[4];
  __shared__ float sscale;
  int wid = t >> 6, lane = t & 63;
  if (lane == 0) sred[wid] = ss;
  __syncthreads();
  if (t == 0) {
    float tot = sred[0] + sred[1] + sred[2] + sred[3];
    sscale = rsqrtf(tot * (1.f/Dsz) + 1e-6f);
  }
  __syncthreads();
  float sc = sscale;
  out[base + t]       = w[t]       * v0 * sc;
  out[base + t + 256] = w[t + 256] * v1 * sc;
}

// ---------------- fp32-in bf16 MFMA GEMM (128x128) — fallback logits ----------------
__global__ __launch_bounds__(256) void k_gemm128(
    const float* __restrict__ A, int lda,
    const float* __restrict__ B, int ldb,
    const float* __restrict__ bias,
    float* __restrict__ C, int ldc,
    int M, int N, int K)
{
  __shared__ __align__(16) unsigned short As[128][40];
  __shared__ __align__(16) unsigned short Bs[128][40];
  int t = threadIdx.x;
  int m0 = blockIdx.y * 128;
  int n0 = blockIdx.x * 128;
  int wid = t >> 6, lane = t & 63;
  int wr = wid >> 1, wc = wid & 1;
  f32x4 acc[4][4] = {};
  int tr = t >> 3;
  int tc = (t & 7) * 4;

  for (int k0 = 0; k0 < K; k0 += 32) {
    #pragma unroll
    for (int rr = 0; rr < 128; rr += 32) {
      int row = rr + tr;
      float4 av = *reinterpret_cast<const float4*>(A + (size_t)(m0 + row)*lda + k0 + tc);
      ushort4 ap; ap.x = f2bf(av.x); ap.y = f2bf(av.y); ap.z = f2bf(av.z); ap.w = f2bf(av.w);
      *reinterpret_cast<ushort4*>(&As[row][tc]) = ap;
      int bn = n0 + row;
      float4 bv = make_float4(0.f, 0.f, 0.f, 0.f);
      if (bn < N) bv = *reinterpret_cast<const float4*>(B + (size_t)bn*ldb + k0 + tc);
      ushort4 bp; bp.x = f2bf(bv.x); bp.y = f2bf(bv.y); bp.z = f2bf(bv.z); bp.w = f2bf(bv.w);
      *reinterpret_cast<ushort4*>(&Bs[row][tc]) = bp;
    }
    __syncthreads();
    int kc = (lane >> 4) * 8;
    int ra = lane & 15;
    short8 af[4], bf_[4];
    #pragma unroll
    for (int mt = 0; mt < 4; ++mt)
      af[mt] = *reinterpret_cast<const short8*>(&As[wr*64 + mt*16 + ra][kc]);
    #pragma unroll
    for (int nt = 0; nt < 4; ++nt)
      bf_[nt] = *reinterpret_cast<const short8*>(&Bs[wc*64 + nt*16 + ra][kc]);
    #pragma unroll
    for (int mt = 0; mt < 4; ++mt)
      #pragma unroll
      for (int nt = 0; nt < 4; ++nt)
        acc[mt][nt] = __builtin_amdgcn_mfma_f32_16x16x32_bf16(af[mt], bf_[nt], acc[mt][nt], 0, 0, 0);
    __syncthreads();
  }

  #pragma unroll
  for (int mt = 0; mt < 4; ++mt) {
    #pragma unroll
    for (int nt = 0; nt < 4; ++nt) {
      int n = n0 + wc*64 + nt*16 + (lane & 15);
      if (n >= N) continue;
      float bv = bias ? bias[n] : 0.f;
      #pragma unroll
      for (int j = 0; j < 4; ++j) {
        int m = m0 + wr*64 + mt*16 + (lane >> 4)*4 + j;
        C[(size_t)m*ldc + n] = acc[mt][nt][j] + bv;
      }
    }
  }
}

// ---------------- 64x64-tile GEMM body ----------------
template<int OP, int NADD>
DEV void gemm64_body(unsigned short (*As)[40], unsigned short (*Bs)[40],
                     const float* __restrict__ A, int lda,
                     const float* __restrict__ B, int ldb,
                     const float* __restrict__ bias,
                     float* __restrict__ C, int ldc,
                     int K, int m0, int n0, int t,
                     const float* __restrict__ add1,
                     const float* __restrict__ add2,
                     const float* __restrict__ add3)
{
  int lane = t & 63;
  int wid = t >> 6;
  int wr = wid >> 1, wc = wid & 1;
  f32x4 acc[2][2] = {};
  int srow = t >> 2;
  int scb  = (t & 3) * 8;

  const float* apg = A + (size_t)(m0 + srow)*lda + scb;
  const float* bpg = B + (size_t)(n0 + srow)*ldb + scb;

  for (int k0 = 0; k0 < K; k0 += 32) {
    float4 a0 = *reinterpret_cast<const float4*>(apg + k0);
    float4 a1 = *reinterpret_cast<const float4*>(apg + k0 + 4);
    float4 b0 = *reinterpret_cast<const float4*>(bpg + k0);
    float4 b1 = *reinterpret_cast<const float4*>(bpg + k0 + 4);
    short8 av, bv;
    av[0]=f2bf(a0.x); av[1]=f2bf(a0.y); av[2]=f2bf(a0.z); av[3]=f2bf(a0.w);
    av[4]=f2bf(a1.x); av[5]=f2bf(a1.y); av[6]=f2bf(a1.z); av[7]=f2bf(a1.w);
    bv[0]=f2bf(b0.x); bv[1]=f2bf(b0.y); bv[2]=f2bf(b0.z); bv[3]=f2bf(b0.w);
    bv[4]=f2bf(b1.x); bv[5]=f2bf(b1.y); bv[6]=f2bf(b1.z); bv[7]=f2bf(b1.w);
    *reinterpret_cast<short8*>(&As[srow][scb]) = av;
    *reinterpret_cast<short8*>(&Bs[srow][scb]) = bv;
    __syncthreads();
    int kc = (lane >> 4) * 8;
    int ra = lane & 15;
    short8 af[2], bf_[2];
    #pragma unroll
    for (int mt = 0; mt < 2; ++mt)
      af[mt] = *reinterpret_cast<const short8*>(&As[wr*32 + mt*16 + ra][kc]);
    #pragma unroll
    for (int nt = 0; nt < 2; ++nt)
      bf_[nt] = *reinterpret_cast<const short8*>(&Bs[wc*32 + nt*16 + ra][kc]);
    #pragma unroll
    for (int mt = 0; mt < 2; ++mt)
      #pragma unroll
      for (int nt = 0; nt < 2; ++nt)
        acc[mt][nt] = __builtin_amdgcn_mfma_f32_16x16x32_bf16(af[mt], bf_[nt], acc[mt][nt], 0, 0, 0);
    __syncthreads();
  }

  #pragma unroll
  for (int mt = 0; mt < 2; ++mt) {
    #pragma unroll
    for (int nt = 0; nt < 2; ++nt) {
      int n = n0 + wc*32 + nt*16 + (lane & 15);
      float bv = bias ? bias[n] : 0.f;
      #pragma unroll
      for (int j = 0; j < 4; ++j) {
        int m = m0 + wr*32 + mt*16 + (lane >> 4)*4 + j;
        float v = acc[mt][nt][j] + bv;
        if (OP == 1) v = v / (1.f + expf(-v));
        else if (OP == 2) v = 0.5f * v * (1.f + erff(v * 0.70710678118f));
        size_t idx = (size_t)m*ldc + n;
        if (NADD >= 1) v += add1[idx];
        if (NADD >= 2) v += add2[idx];
        if (NADD >= 3) v += add3[idx];
        C[idx] = v;
      }
    }
  }
}

// ---------------- standalone 64x64 GEMM ----------------
template<int OP, int NADD>
__global__ __launch_bounds__(256) void k_gemm64(
    const float* __restrict__ A, int lda,
    const float* __restrict__ B, int ldb,
    const float* __restrict__ bias,
    float* __restrict__ C, int ldc, int K,
    const float* add1, const float* add2, const float* add3)
{
  __shared__ __align__(16) unsigned short As[64][40];
  __shared__ __align__(16) unsigned short Bs[64][40];
  gemm64_body<OP,NADD>(As, Bs, A, lda, B, ldb, bias, C, ldc, K,
                       blockIdx.y*64, blockIdx.x*64, threadIdx.x, add1, add2, add3);
}

// ---------------- fused: dwconv (blocks x>=6) + 3 recurrence projections ----------------
__global__ __launch_bounds__(256) void k_dwproj3(
    const float* __restrict__ xn,
    const float* __restrict__ rin_w, const float* __restrict__ rin_b,
    const float* __restrict__ rf_w,  const float* __restrict__ rf_b,
    const float* __restrict__ ru_w,  const float* __restrict__ ru_b,
    float* __restrict__ mu, float* __restrict__ fx, float* __restrict__ ux,
    const float* __restrict__ dw_w, const float* __restrict__ dw_b,
    float* __restrict__ dout, int dil)
{
  __shared__ __align__(16) unsigned short As[64][40];
  __shared__ __align__(16) unsigned short Bs[64][40];
  if (blockIdx.x >= 6) {
    int row = (blockIdx.x - 6)*32 + blockIdx.y;
    int b = row >> 10, s = row & (Ssz-1);
    int t = threadIdx.x;
    #pragma unroll
    for (int dd = 0; dd < 2; ++dd) {
      int d = t + dd*256;
      float acc = dw_b[d];
      #pragma unroll
      for (int j = 0; j < 5; ++j) {
        int sp = s - (4 - j) * dil;
        if (sp >= 0) acc += dw_w[d*5 + j] * xn[((size_t)(b*Ssz + sp))*Dsz + d];
      }
      dout[(size_t)row*Dsz + d] = acc;
    }
    return;
  }
  int which = blockIdx.x >> 1;          // 0:mu 1:fx 2:ux
  int n0 = (blockIdx.x & 1) * 64;
  int m0 = blockIdx.y * 64;
  if (which == 0)
    gemm64_body<1,0>(As, Bs, xn, Dsz, rin_w, Dsz, rin_b, mu, DMs, Dsz, m0, n0, threadIdx.x, nullptr, nullptr, nullptr);
  else if (which == 1)
    gemm64_body<0,0>(As, Bs, xn, Dsz, rf_w, 640, rf_b, fx, DMs, Dsz, m0, n0, threadIdx.x, nullptr, nullptr, nullptr);
  else
    gemm64_body<0,0>(As, Bs, xn, Dsz, ru_w, 640, ru_b, ux, DMs, Dsz, m0, n0, threadIdx.x, nullptr, nullptr, nullptr);
}

// ---------------- batched expert pair (+ optional folded router softmax) ----------------
template<int OP, int RT>
__global__ __launch_bounds__(256) void k_expair(
    const float* __restrict__ A0, const float* __restrict__ A1, int lda,
    const float* __restrict__ B0, const float* __restrict__ B1, int ldb,
    const float* __restrict__ bias0, const float* __restrict__ bias1,
    float* __restrict__ C0, float* __restrict__ C1, int ldc, int K,
    const float* __restrict__ rtw, const float* __restrict__ rtb,
    float* __restrict__ rg)
{
  __shared__ __align__(16) unsigned short As[64][40];
  __shared__ __align__(16) unsigned short Bs[64][40];
  if (RT && blockIdx.x >= 16) {
    int lane = threadIdx.x & 63, wid = threadIdx.x >> 6;
    #pragma unroll 1
    for (int it = 0; it < 16; ++it) {
      int row = blockIdx.y*64 + it*4 + wid;
      const float* hp = A0 + (size_t)row*Dsz;
      float a0 = 0.f, a1 = 0.f;
      #pragma unroll
      for (int k = lane; k < Dsz; k += 64) {
        float hv = hp[k];
        a0 += hv * rtw[k];
        a1 += hv * rtw[Dsz + k];
      }
      #pragma unroll
      for (int off = 32; off > 0; off >>= 1) {
        a0 += __shfl_down(a0, off);
        a1 += __shfl_down(a1, off);
      }
      if (lane == 0) {
        a0 += rtb[0]; a1 += rtb[1];
        float mx = fmaxf(a0, a1);
        float e0 = expf(a0 - mx), e1 = expf(a1 - mx);
        float s = e0 + e1;
        rg[row*2]     = e0 / s;
        rg[row*2 + 1] = e1 / s;
      }
    }
    return;
  }
  int e = blockIdx.x >> 3;
  int n0 = (blockIdx.x & 7) * 64;
  gemm64_body<OP,0>(As, Bs, e ? A1 : A0, lda, e ? B1 : B0, ldb,
                    e ? bias1 : bias0, e ? C1 : C0, ldc, K,
                    blockIdx.y*64, n0, threadIdx.x, nullptr, nullptr, nullptr);
}

// ---------------- bf16-in GEMM for logits (128x128, padded LDS, XCD swizzle) ----------------
// CLOSED: padded reg-staged beats the gll16 linear-LDS variant (+13us, A/B r8 vs r9).
__global__ __launch_bounds__(256) void k_gemm_logits(
    const unsigned short* __restrict__ A, const unsigned short* __restrict__ B,
    float* __restrict__ C, int M, int N, int K)
{
  __shared__ __align__(16) unsigned short As[128][40];
  __shared__ __align__(16) unsigned short Bs[128][40];
  int t = threadIdx.x;
  // XCD-aware swizzle: grid is fixed 16 x 393 = 6288 blocks, 6288 % 8 == 0 -> bijective.
  int lin = blockIdx.x + blockIdx.y * 16;
  int swz = (lin & 7) * 786 + (lin >> 3);
  int m0 = (swz & 15) * 128;
  int n0 = (swz >> 4) * 128;
  int wid = t >> 6, lane = t & 63;
  int wr = wid >> 1, wc = wid & 1;
  f32x4 acc[4][4] = {};
  int srow = t >> 1;
  int scb  = (t & 1) * 16;

  const unsigned short* ap = A + (size_t)(m0 + srow)*K + scb;
  int bn = n0 + srow; if (bn >= N) bn = N - 1;
  const unsigned short* bp = B + (size_t)bn*K + scb;

  for (int k0 = 0; k0 < K; k0 += 32) {
    short8 a0 = *reinterpret_cast<const short8*>(ap + k0);
    short8 a1 = *reinterpret_cast<const short8*>(ap + k0 + 8);
    short8 b0 = *reinterpret_cast<const short8*>(bp + k0);
    short8 b1 = *reinterpret_cast<const short8*>(bp + k0 + 8);
    *reinterpret_cast<short8*>(&As[srow][scb])     = a0;
    *reinterpret_cast<short8*>(&As[srow][scb + 8]) = a1;
    *reinterpret_cast<short8*>(&Bs[srow][scb])     = b0;
    *reinterpret_cast<short8*>(&Bs[srow][scb + 8]) = b1;
    __syncthreads();
    int kc = (lane >> 4) * 8;
    int ra = lane & 15;
    short8 af[4], bf_[4];
    #pragma unroll
    for (int mt = 0; mt < 4; ++mt)
      af[mt] = *reinterpret_cast<const short8*>(&As[wr*64 + mt*16 + ra][kc]);
    #pragma unroll
    for (int nt = 0; nt < 4; ++nt)
      bf_[nt] = *reinterpret_cast<const short8*>(&Bs[wc*64 + nt*16 + ra][kc]);
    #pragma unroll
    for (int mt = 0; mt < 4; ++mt)
      #pragma unroll
      for (int nt = 0; nt < 4; ++nt)
        acc[mt][nt] = __builtin_amdgcn_mfma_f32_16x16x32_bf16(af[mt], bf_[nt], acc[mt][nt], 0, 0, 0);
    __syncthreads();
  }

  #pragma unroll
  for (int mt = 0; mt < 4; ++mt) {
    #pragma unroll
    for (int nt = 0; nt < 4; ++nt) {
      int n = n0 + wc*64 + nt*16 + (lane & 15);
      if (n >= N) continue;
      #pragma unroll
      for (int j = 0; j < 4; ++j) {
        int m = m0 + wr*64 + mt*16 + (lane >> 4)*4 + j;
        C[(size_t)m*N + n] = acc[mt][nt][j];
      }
    }
  }
}

// ---------------- fused: MFMA scan v10 (blocks 0,1) + two 64² GEMMs ----------------
// Scan loop FROZEN: serial latency chain ~790cyc/step (not HBM-bound: 1.7%; not
// MFMA-bound: 4x MFMA cut moved nothing); 5 structural probes null/negative.
__global__ __launch_bounds__(256, 2) void k_scan_fused(
    const float* __restrict__ rf_w, const float* __restrict__ ru_w,
    const float* __restrict__ fx, const float* __restrict__ ux,
    const float* __restrict__ mu, float* __restrict__ Mout,
    const float* __restrict__ g1A, const float* __restrict__ g1B, int g1ldb,
    const float* __restrict__ g1bias, float* __restrict__ g1C,
    const float* __restrict__ g2A, const float* __restrict__ g2B, int g2ldb,
    const float* __restrict__ g2bias, float* __restrict__ g2C)
{
  __shared__ __align__(16) unsigned short As[64][40];
  __shared__ __align__(16) unsigned short Bs[64][40];
  __shared__ __align__(16) unsigned char mf8[2][DMs];

  if (blockIdx.x >= 2) {
    int bid = blockIdx.x - 2;
    int which = bid >> 8;
    int idx = bid & 255;
    int n0 = (idx & 7) * 64;
    int m0 = (idx >> 3) * 64;
    if (which == 0)
      gemm64_body<0,0>(As, Bs, g1A, Dsz, g1B, g1ldb, g1bias, g1C, Dsz, Dsz, m0, n0, threadIdx.x, nullptr, nullptr, nullptr);
    else
      gemm64_body<0,0>(As, Bs, g2A, Dsz, g2B, g2ldb, g2bias, g2C, Dsz, Dsz, m0, n0, threadIdx.x, nullptr, nullptr, nullptr);
    return;
  }

  // scan path: latency-critical; win pipe arbitration vs co-resident GEMM waves
  __builtin_amdgcn_s_setprio(1);

  int b = blockIdx.x;
  int t = threadIdx.x;
  int l = t & 63;
  int w = t >> 6;
  int g = l >> 4;
  int i16 = l & 15;

  // Weights in fp8 e4m3: lane l holds row (tile, i16), k = g*32 .. g*32+31 (32 bytes = 8 VGPRs).
  int8v w8[4];
  #pragma unroll
  for (int rt = 0; rt < 4; ++rt) {
    const float* src = (rt < 2 ? rf_w : ru_w) + (size_t)(w*32 + (rt&1)*16 + i16)*640 + 512 + g*32;
    int8v v;
    #pragma unroll
    for (int bq = 0; bq < 8; ++bq) {
      float4 f4 = *reinterpret_cast<const float4*>(src + bq*4);
      int rr = 0;
      rr = __builtin_amdgcn_cvt_pk_fp8_f32(f4.x, f4.y, rr, false);
      rr = __builtin_amdgcn_cvt_pk_fp8_f32(f4.z, f4.w, rr, true);
      v[bq] = rr;
    }
    w8[rt] = v;
  }

  if (t < DMs) mf8[0][t] = 0;   // fp8 0.0 == 0x00

  bool writer = (i16 & 4) == 0;
  int rho = ((i16 >> 3) << 4) + (g << 2) + (i16 & 3);
  int r = w*32 + rho;
  bool jb0 = (i16 & 1), jb1 = (i16 & 2), ab = (i16 & 8);

  const float* fxp = fx + (size_t)b*Ssz*DMs + r;
  const float* uxp = ux + (size_t)b*Ssz*DMs + r;
  const float* mup = mu + (size_t)b*Ssz*DMs + r;
  float* mo = Mout + (size_t)b*Ssz*DMs + r;
  float mreg = 0.f, fxv = 0.f, uxv = 0.f, muv = 0.f;
  __syncthreads();
  if (writer) { fxv = fxp[0]; uxv = uxp[0]; muv = mup[0]; }

  const int SC = 0x7F7F7F7F;    // E8M0 = 127 -> scale 1.0 in all 4 bytes
  int cur = 0;
  for (int step = 0; step < Ssz; ++step) {
    int4v blo = *reinterpret_cast<const int4v*>(&mf8[cur][g*32]);
    int4v bhi = *reinterpret_cast<const int4v*>(&mf8[cur][g*32 + 16]);
    int8v bm;
    bm[0]=blo[0]; bm[1]=blo[1]; bm[2]=blo[2]; bm[3]=blo[3];
    bm[4]=bhi[0]; bm[5]=bhi[1]; bm[6]=bhi[2]; bm[7]=bhi[3];

    f32x4 zero = {0.f, 0.f, 0.f, 0.f};
    f32x4 a0 = __builtin_amdgcn_mfma_scale_f32_16x16x128_f8f6f4(w8[0], bm, zero, 0, 0, 0, SC, 0, SC);
    f32x4 a1 = __builtin_amdgcn_mfma_scale_f32_16x16x128_f8f6f4(w8[1], bm, zero, 0, 0, 0, SC, 0, SC);
    f32x4 a2 = __builtin_amdgcn_mfma_scale_f32_16x16x128_f8f6f4(w8[2], bm, zero, 0, 0, 0, SC, 0, SC);
    f32x4 a3 = __builtin_amdgcn_mfma_scale_f32_16x16x128_f8f6f4(w8[3], bm, zero, 0, 0, 0, SC, 0, SC);

    float f01 = jb0 ? a0[1] : a0[0];
    float f23 = jb0 ? a0[3] : a0[2];
    float fa0 = jb1 ? f23 : f01;
    float f01b = jb0 ? a1[1] : a1[0];
    float f23b = jb0 ? a1[3] : a1[2];
    float fa1 = jb1 ? f23b : f01b;
    float zf = ab ? fa1 : fa0;
    float u01 = jb0 ? a2[1] : a2[0];
    float u23 = jb0 ? a2[3] : a2[2];
    float ua0 = jb1 ? u23 : u01;
    float u01b = jb0 ? a3[1] : a3[0];
    float u23b = jb0 ? a3[3] : a3[2];
    float ua1 = jb1 ? u23b : u01b;
    float zu = ab ? ua1 : ua0;

    if (writer) {
      float f = __builtin_amdgcn_rcpf(1.f + __expf(-(zf + fxv)));
      float u = __builtin_amdgcn_rcpf(1.f + __expf(-(zu + uxv)));
      float mnew = f*mreg + u*muv;
      mreg = mnew;
      int p8 = __builtin_amdgcn_cvt_pk_fp8_f32(mnew, mnew, 0, false);
      mf8[cur^1][r] = (unsigned char)(p8 & 0xff);
      mo[(size_t)step*DMs] = mnew;
      if (step < Ssz-1) {
        fxv = fxp[(size_t)(step+1)*DMs];
        uxv = uxp[(size_t)(step+1)*DMs];
        muv = mup[(size_t)(step+1)*DMs];
      }
    }
    asm volatile("s_waitcnt lgkmcnt(0)\n\ts_barrier" ::: "memory");
    cur ^= 1;
  }
}

// ---------------- host ----------------
extern "C" void kernel_launch(void* const* d_in, const int* in_sizes, int n_in,
                              void* d_out, int out_size, void* d_ws, size_t ws_size,
                              hipStream_t stream)
{
  const int*   tokens = (const int*)  d_in[0];
  const float* embed  = (const float*)d_in[1];
  const float* norm_w = (const float*)d_in[2];
  const float* dw_w   = (const float*)d_in[3];
  const float* dw_b   = (const float*)d_in[4];
  const float* pw_w   = (const float*)d_in[5];
  const float* pw_b   = (const float*)d_in[6];
  const float* rin_w  = (const float*)d_in[7];
  const float* rin_b  = (const float*)d_in[8];
  const float* rf_w   = (const float*)d_in[9];
  const float* rf_b   = (const float*)d_in[10];
  const float* ru_w   = (const float*)d_in[11];
  const float* ru_b   = (const float*)d_in[12];
  const float* ro_w   = (const float*)d_in[13];
  const float* ro_b   = (const float*)d_in[14];
  const float* rt_w   = (const float*)d_in[15];
  const float* rt_b   = (const float*)d_in[16];
  const float* e1_w   = (const float*)d_in[17];
  const float* e1_b   = (const float*)d_in[18];
  const float* e2_w   = (const float*)d_in[19];
  const float* e2_b   = (const float*)d_in[20];
  const float* fn_w   = (const float*)d_in[21];
  const float* fd_w   = (const float*)d_in[22];
  const float* fd_b   = (const float*)d_in[23];
  const float* fu_w   = (const float*)d_in[24];
  const float* fu_b   = (const float*)d_in[25];
  const float* fnorm  = (const float*)d_in[26];
  float* out = (float*)d_out;

  float* ws = (float*)d_ws;
  const size_t M1 = 1u << 20;
  float* x   = ws + 0*M1;
  float* xn  = ws + 1*M1;
  float* b2  = ws + 2*M1;
  float* b3  = ws + 3*M1;
  float* h   = ws + 4*M1;
  float* b5  = ws + 5*M1;
  float* b6  = ws + 6*M1;          // expert-1 e2 output (ROWS x Dsz = exactly M1 floats)
  float* mu  = ws + 7*M1;
  float* fx  = ws + 7*M1 + 262144;
  float* ux  = ws + 7*M1 + 2*262144;
  float* Mb  = ws + 7*M1 + 3*262144;
  float* g   = ws + 8*M1;          // ROWS x DMs only (262144 floats) — rg lives right after!
  float* rg  = ws + 8*M1 + 262144;
  const size_t EMB_ELEMS = (size_t)Vsz * Dsz;
  unsigned short* embb = (unsigned short*)(ws + 9*M1);
  bool big = ws_size >= (size_t)(9*M1*4) + EMB_ELEMS*2 + 1024;

  const int dils[4] = {1, 1, 2, 4};

  k_embed_rope<<<ROWS, 256, 0, stream>>>(tokens, embed, x);

  for (int i = 0; i < 4; ++i) {
    k_rmsnorm<<<ROWS,256,0,stream>>>(x, norm_w + i*Dsz, xn);
    // fused: dwconv (xn->b2) + recurrence projections mu/fx/ux, one dispatch
    {
      dim3 gr(70, 32);
      k_dwproj3<<<gr,256,0,stream>>>(xn,
          rin_w + (size_t)i*DMs*Dsz, rin_b + i*DMs,
          rf_w  + (size_t)i*DMs*640, rf_b  + i*DMs,
          ru_w  + (size_t)i*DMs*640, ru_b  + i*DMs,
          mu, fx, ux,
          dw_w + i*Dsz*5, dw_b + i*Dsz, b2, dils[i]);
    }
    // fused: scan (blocks 0,1) + pw GEMM (b2->b3) + ox GEMM (xn->b5)
    k_scan_fused<<<2 + 512, 256, 0, stream>>>(
        rf_w + (size_t)i*DMs*640, ru_w + (size_t)i*DMs*640, fx, ux, mu, Mb,
        b2, pw_w + (size_t)i*Dsz*Dsz, Dsz, pw_b + i*Dsz, b3,
        xn, ro_w + (size_t)i*Dsz*640, 640, ro_b + i*Dsz, b5);
    // wom projection, fused: h = gemm + xc + xn + ox
    {
      dim3 gr(Dsz/64, ROWS/64);
      k_gemm64<0,3><<<gr,256,0,stream>>>(Mb,DMs, ro_w + (size_t)i*Dsz*640 + 512,640, nullptr, h,Dsz, DMs, b3, xn, b5);
    }
    // experts pair-batched; router softmax folded into the e1 dispatch (blocks x==16)
    {
      dim3 ge1(17, ROWS/64), ge0(16, ROWS/64);
      k_expair<1,1><<<ge1,256,0,stream>>>(h, h, Dsz,
          e1_w + (size_t)(i*2+0)*Dsz*Dsz, e1_w + (size_t)(i*2+1)*Dsz*Dsz, Dsz,
          e1_b + (i*2+0)*Dsz, e1_b + (i*2+1)*Dsz,
          b2, b5, Dsz, Dsz,
          rt_w + i*2*Dsz, rt_b + i*2, rg);
      k_expair<0,0><<<ge0,256,0,stream>>>(b2, b5, Dsz,
          e2_w + (size_t)(i*2+0)*Dsz*Dsz, e2_w + (size_t)(i*2+1)*Dsz*Dsz, Dsz,
          e2_b + (i*2+0)*Dsz, e2_b + (i*2+1)*Dsz,
          b3, b6, Dsz, Dsz,
          nullptr, nullptr, nullptr);
    }
    // hn = rmsnorm(h + r0*e0 + r1*e1)
    k_combine_norm<<<ROWS,256,0,stream>>>(h, b3, b6, rg, fn_w + i*Dsz, xn);
    // FFN: g = gelu(...); x = x + xn + g@fu^T + fu_b
    {
      dim3 g1(DMs/64, ROWS/64), g2(Dsz/64, ROWS/64);
      k_gemm64<2,0><<<g1,256,0,stream>>>(xn,Dsz, fd_w + (size_t)i*DMs*Dsz,Dsz, fd_b + i*DMs, g,DMs, Dsz, nullptr,nullptr,nullptr);
      k_gemm64<0,2><<<g2,256,0,stream>>>(g,DMs, fu_w + (size_t)i*Dsz*DMs,DMs, fu_b + i*Dsz, x,Dsz, DMs, x, xn, nullptr);
    }
  }

  if (big) {
    unsigned short* xnb = (unsigned short*)b3;
    // fused: final rmsnorm->bf16 (blocks 0..2047) + embed f2b (blocks 2048..4095)
    k_final_prep<<<ROWS + 2048, 256, 0, stream>>>(x, fnorm, xnb, embed, embb, (int)(EMB_ELEMS/8));
    dim3 grid(ROWS/128, (Vsz + 127)/128);
    k_gemm_logits<<<grid,256,0,stream>>>(xnb, embb, out, ROWS, Vsz, Dsz);
  } else {
    k_rmsnorm<<<ROWS,256,0,stream>>>(x, fnorm, xn);
    dim3 grid((Vsz + 127)/128, ROWS/128);
    k_gemm128<<<grid,256,0,stream>>>(xn,Dsz, embed,Dsz, nullptr, out,Vsz, ROWS,Vsz,Dsz);
  }
}